// Round 13
// baseline (200.731 us; speedup 1.0000x reference)
//
#include <hip/hip_runtime.h>
#include <hip/hip_bf16.h>
#include <stdint.h>
#include <math.h>

#define N_ROWS 4096
#define H_DIM  1024
#define V_SIZE 32000
#define IGNORE_INDEX (-100)

#define BV 128   // vocab tile (MFMA M dim)
#define BN 128   // row tile   (MFMA N dim)
#define BKB 128  // K-tile bytes = 128 fp8 elements
#define N_TILES (N_ROWS / BN)   // 32
#define V_TILES (V_SIZE / BV)   // 250
#define K_TILES (H_DIM / BKB)   // 8

#define WMUL 16.0f               // W pre-scale before e4m3 (keeps it in normal range)
#define DESCALE (1.0f / 16.0f)   // undo WMUL on logits

#define TW_BLOCKS ((V_SIZE / 64) * (H_DIM / 64))   // 8000 transpose blocks
#define CX_BLOCKS (N_ROWS * H_DIM / 4 / 256)       // 4096 convert blocks

typedef int   intx4  __attribute__((ext_vector_type(4)));
typedef int   intx8  __attribute__((ext_vector_type(8)));
typedef float floatx4 __attribute__((ext_vector_type(4)));

// ---- OCP e4m3fn encode (manual RNE; no builtin dependency) -----------------
static __device__ __forceinline__ uint32_t enc_e4m3(float f) {
    uint32_t u = __float_as_uint(f);
    uint32_t s = (u >> 24) & 0x80;
    float a = fabsf(f);
    if (a >= 448.f) return s | 0x7E;                 // clamp to max normal
    if (a < 0.015625f) {                             // subnormal: m = rne(a*512)
        int m = __float2int_rn(a * 512.f);
        return s | (uint32_t)(m >= 8 ? 0x08 : m);
    }
    uint32_t au = u & 0x7FFFFFFFu;
    au += 0x7FFFFu + ((au >> 20) & 1u);              // RNE into bit 20
    if (au >= 0x43E00000u) return s | 0x7E;          // rounded up past 448
    uint32_t e = ((au >> 23) & 0xFF) - 127 + 7;
    uint32_t m = (au >> 20) & 7;
    return s | (e << 3) | m;
}
static __device__ __forceinline__ float dec_e4m3(uint32_t b) {
    uint32_t sg = b & 0x80, e = (b >> 3) & 15, m = b & 7;
    float v = e ? ldexpf((float)(8 + m), (int)e - 10)
                : (float)m * 0.001953125f;           // 2^-9
    return sg ? -v : v;
}

static __device__ __forceinline__ void gload_lds16(const void* g, void* l) {
    __builtin_amdgcn_global_load_lds(
        (const __attribute__((address_space(1))) unsigned int*)g,
        (__attribute__((address_space(3))) unsigned int*)l,
        16, 0, 0);
}

// ---- K1: fused prep: W[H][V] fp32 -> Wq[V][H] e4m3(W*16); x -> e4m3(x) -----
__global__ void k_prep(const float* __restrict__ W, unsigned char* __restrict__ wq,
                       const float* __restrict__ x, unsigned char* __restrict__ xq) {
    int b = blockIdx.x;
    if (b < TW_BLOCKS) {
        const int t = threadIdx.x;
        const int kq = t & 15;
        const int vq = t >> 4;
        const int k0 = (b / (V_SIZE / 64)) * 64 + kq * 4;
        const int v0 = (b % (V_SIZE / 64)) * 64 + vq * 4;

        const float* p = W + (size_t)k0 * V_SIZE + v0;
        float4 r0 = *(const float4*)(p);
        float4 r1 = *(const float4*)(p + V_SIZE);
        float4 r2 = *(const float4*)(p + 2 * V_SIZE);
        float4 r3 = *(const float4*)(p + 3 * V_SIZE);

        uint32_t w0 = enc_e4m3(r0.x * WMUL) | (enc_e4m3(r1.x * WMUL) << 8) | (enc_e4m3(r2.x * WMUL) << 16) | (enc_e4m3(r3.x * WMUL) << 24);
        uint32_t w1 = enc_e4m3(r0.y * WMUL) | (enc_e4m3(r1.y * WMUL) << 8) | (enc_e4m3(r2.y * WMUL) << 16) | (enc_e4m3(r3.y * WMUL) << 24);
        uint32_t w2 = enc_e4m3(r0.z * WMUL) | (enc_e4m3(r1.z * WMUL) << 8) | (enc_e4m3(r2.z * WMUL) << 16) | (enc_e4m3(r3.z * WMUL) << 24);
        uint32_t w3 = enc_e4m3(r0.w * WMUL) | (enc_e4m3(r1.w * WMUL) << 8) | (enc_e4m3(r2.w * WMUL) << 16) | (enc_e4m3(r3.w * WMUL) << 24);

        unsigned char* q = wq + (size_t)v0 * H_DIM + k0;
        *(uint32_t*)(q)             = w0;
        *(uint32_t*)(q + H_DIM)     = w1;
        *(uint32_t*)(q + 2 * H_DIM) = w2;
        *(uint32_t*)(q + 3 * H_DIM) = w3;
    } else {
        int i = ((b - TW_BLOCKS) * 256 + threadIdx.x) * 4;
        float4 v = *(const float4*)(x + i);
        uint32_t o = enc_e4m3(v.x)
                   | (enc_e4m3(v.y) << 8)
                   | (enc_e4m3(v.z) << 16)
                   | (enc_e4m3(v.w) << 24);
        *(uint32_t*)(xq + i) = o;
    }
}

// ---- K3: fused fp8 GEMM (r11 geometry, mfma_scale 16x16x128, scales=1.0) ---
// logits[v][n] = (sum_k dec(Wq[v][k])*dec(xq[n][k])) * DESCALE
// Spart[vt][n] = sum_{v in tile} exp(logit)
// Staging/swizzle byte-identical to r3/r11 (measured 0 conflicts): 128 rows x
// 128B, 8 16B slots/row, slot ^= (row&7).  Fragment: row = lane&15,
// k = (lane>>4)*32 + i (32 contiguous bytes = 2 b128 slots; 16-row reads ->
// 2-way bank aliasing = free, the only conflict-free pattern at this stride).
// MFMA: f8f6f4 fmt 0/0 = e4m3 x e4m3, scale operands 0x7f7f7f7f (=1.0) ->
// pure fp8 GEMM at the MX rate (4661 TF vs i8 3944).
__global__ __launch_bounds__(256, 2) void k_gemm_expsum(
    const unsigned char* __restrict__ wq,
    const unsigned char* __restrict__ xq,
    float* __restrict__ Spart)
{
    __shared__ __align__(16) unsigned char smbuf[2][BV * BKB];  // 32KB total
    unsigned char* a_sm = smbuf[0];
    unsigned char* b_sm = smbuf[1];

    const int bid = blockIdx.x;
    const int nt = bid & (N_TILES - 1);
    const int vt = bid >> 5;
    const int v0 = vt * BV;
    const int n0 = nt * BN;

    const int t = threadIdx.x;
    const int lane = t & 63;
    const int w = t >> 6;       // wave 0..3
    const int wv = w >> 1;      // v half
    const int wn = w & 1;       // n half

    const int srcColb = (((lane & 7) ^ (lane >> 3)) << 4);
    const unsigned char* aG = wq + (size_t)v0 * H_DIM;
    const unsigned char* bG = xq + (size_t)n0 * H_DIM;

    // loop-invariant LDS addressing: lane's k-window = (lane>>4)*32 .. +31
    const int j32 = (lane >> 4) << 5;       // 0,32,64,96
    int arow[4], brow[4];                   // row*128 bases and row-swizzle
    int aswz[4], bswz[4];
#pragma unroll
    for (int m = 0; m < 4; ++m) {
        int row = wv * 64 + m * 16 + (lane & 15);
        arow[m] = row * 128;
        aswz[m] = (row & 7) << 4;
    }
#pragma unroll
    for (int n = 0; n < 4; ++n) {
        int row = wn * 64 + n * 16 + (lane & 15);
        brow[n] = row * 128;
        bswz[n] = (row & 7) << 4;
    }

    floatx4 acc[4][4] = {};

    for (int kt = 0; kt < K_TILES; ++kt) {
        const size_t kb = (size_t)kt * BKB;
#pragma unroll
        for (int c = 0; c < 4; ++c) {
            int row = w * 32 + c * 8 + (lane >> 3);
            gload_lds16(aG + (size_t)row * H_DIM + kb + srcColb,
                        a_sm + (w * 4 + c) * 1024);
        }
#pragma unroll
        for (int c = 0; c < 4; ++c) {
            int row = w * 32 + c * 8 + (lane >> 3);
            gload_lds16(bG + (size_t)row * H_DIM + kb + srcColb,
                        b_sm + (w * 4 + c) * 1024);
        }
        asm volatile("s_waitcnt vmcnt(0)" ::: "memory");
        __syncthreads();

        intx8 bf8[4];
#pragma unroll
        for (int n = 0; n < 4; ++n) {
            intx4 lo = *(const intx4*)(b_sm + brow[n] + ((j32) ^ bswz[n]));
            intx4 hi = *(const intx4*)(b_sm + brow[n] + ((j32 + 16) ^ bswz[n]));
            bf8[n] = __builtin_shufflevector(lo, hi, 0, 1, 2, 3, 4, 5, 6, 7);
        }
#pragma unroll
        for (int m = 0; m < 4; ++m) {
            intx4 lo = *(const intx4*)(a_sm + arow[m] + ((j32) ^ aswz[m]));
            intx4 hi = *(const intx4*)(a_sm + arow[m] + ((j32 + 16) ^ aswz[m]));
            intx8 af8 = __builtin_shufflevector(lo, hi, 0, 1, 2, 3, 4, 5, 6, 7);
#pragma unroll
            for (int n = 0; n < 4; ++n)
                acc[m][n] = __builtin_amdgcn_mfma_scale_f32_16x16x128_f8f6f4(
                    af8, bf8[n], acc[m][n], 0, 0,
                    0, 0x7f7f7f7f, 0, 0x7f7f7f7f);
        }
        __syncthreads();
    }

    // epilogue: descale + exp + column sums. C/D: col=lane&15 (n), row=(lane>>4)*4+r
    float csum[4];
#pragma unroll
    for (int nf = 0; nf < 4; ++nf) {
        float s = 0.f;
#pragma unroll
        for (int m = 0; m < 4; ++m)
#pragma unroll
            for (int r = 0; r < 4; ++r)
                s += __expf(acc[m][nf][r] * DESCALE);
        s += __shfl_xor(s, 16, 64);
        s += __shfl_xor(s, 32, 64);
        csum[nf] = s;
    }
    float* red = (float*)smbuf[0];   // race-free reuse after final barrier
    if (lane < 16) {
#pragma unroll
        for (int nf = 0; nf < 4; ++nf)
            red[wv * BN + wn * 64 + nf * 16 + lane] = csum[nf];
    }
    __syncthreads();
    if (t < BN) {
        float S = red[t] + red[BN + t];
        Spart[(size_t)vt * N_ROWS + n0 + t] = S;
    }
}

// ---- K4: target logits (same fp8 values -> error cancels vs lse) -----------
__global__ void k_tgt(const unsigned char* __restrict__ xq,
                      const unsigned char* __restrict__ wq,
                      const int* __restrict__ tgt,
                      float* __restrict__ tlog)
{
    int w = threadIdx.x >> 6;
    int lane = threadIdx.x & 63;
    int n = blockIdx.x * 4 + w;
    int tg = tgt[n];
    int ts = (tg == IGNORE_INDEX) ? 0 : tg;
    const unsigned char* xr = xq + (size_t)n * H_DIM;
    const unsigned char* wr = wq + (size_t)ts * H_DIM;
    float s = 0.f;
#pragma unroll
    for (int i = 0; i < 4; ++i) {
        uint32_t xa = *(const uint32_t*)(xr + lane * 4 + i * 256);
        uint32_t wa = *(const uint32_t*)(wr + lane * 4 + i * 256);
#pragma unroll
        for (int j = 0; j < 4; ++j)
            s += dec_e4m3((xa >> (8 * j)) & 0xff) * dec_e4m3((wa >> (8 * j)) & 0xff);
    }
#pragma unroll
    for (int off = 32; off; off >>= 1) s += __shfl_xor(s, off, 64);
    if (lane == 0) tlog[n] = s * DESCALE;
}

// ---- K5: per-row loss + block partials -------------------------------------
__global__ void k_rowloss(const float* __restrict__ Spart,
                          const float* __restrict__ tlog,
                          const int* __restrict__ tgt,
                          float* __restrict__ partials)
{
    int n = blockIdx.x * 256 + threadIdx.x;
    float S = 0.f;
    for (int vt2 = 0; vt2 < V_TILES; ++vt2)
        S += Spart[(size_t)vt2 * N_ROWS + n];
    float loss = 0.f;
    int tg = tgt[n];
    if (tg != IGNORE_INDEX) loss = logf(S) - tlog[n];

    __shared__ float sm[256];
    sm[threadIdx.x] = loss;
    __syncthreads();
    for (int s2 = 128; s2 > 0; s2 >>= 1) {
        if (threadIdx.x < s2) sm[threadIdx.x] += sm[threadIdx.x + s2];
        __syncthreads();
    }
    if (threadIdx.x == 0) partials[blockIdx.x] = sm[0];
}

__global__ void k_final(const float* __restrict__ partials, float* __restrict__ out) {
    if (threadIdx.x == 0) {
        float s = 0.f;
        for (int i = 0; i < 16; ++i) s += partials[i];
        out[0] = s;
    }
}

// ---- launch ----------------------------------------------------------------
extern "C" void kernel_launch(void* const* d_in, const int* in_sizes, int n_in,
                              void* d_out, int out_size, void* d_ws, size_t ws_size,
                              hipStream_t stream)
{
    const float* x = (const float*)d_in[0];
    const float* W = (const float*)d_in[1];
    const int* tgt = (const int*)d_in[2];
    float* out = (float*)d_out;

    char* ws = (char*)d_ws;
    size_t off = 0;
    unsigned char* xq = (unsigned char*)(ws + off); off += (size_t)N_ROWS * H_DIM;
    unsigned char* wq = (unsigned char*)(ws + off); off += (size_t)V_SIZE * H_DIM;
    float* Spart = (float*)(ws + off);              off += (size_t)V_TILES * N_ROWS * 4;
    float* tlog  = (float*)(ws + off);              off += (size_t)N_ROWS * 4;
    float* partials = (float*)(ws + off);           off += 64;

    k_prep<<<TW_BLOCKS + CX_BLOCKS, 256, 0, stream>>>(W, wq, x, xq);
    k_gemm_expsum<<<V_TILES * N_TILES, 256, 0, stream>>>(wq, xq, Spart);
    k_tgt<<<N_ROWS / 4, 256, 0, stream>>>(xq, wq, tgt, tlog);
    k_rowloss<<<16, 256, 0, stream>>>(Spart, tlog, tgt, partials);
    k_final<<<1, 64, 0, stream>>>(partials, out);
}